// Round 1
// baseline (3383.399 us; speedup 1.0000x reference)
//
#include <hip/hip_runtime.h>
#include <math.h>

namespace {
constexpr int B_ = 8;
constexpr int N_ = 2048;
constexpr int D_ = 1024;
constexpr float NEGV = -1.0e9f;
constexpr int BT = 128;   // block tile (M and N)
constexpr int KT = 16;    // k tile
}

// ---------------------------------------------------------------------------
// Per-batch valid lengths from the prefix mask. Handles uint8 (1B/elem) and
// int32/float32 (4B/elem) layouts: byte[1]==1 only in the uint8 layout
// (mask[0][1] is true since L >= 1024); int32 value 1 has byte[1]==0.
// ---------------------------------------------------------------------------
__global__ __launch_bounds__(256)
void k_lengths(const unsigned char* __restrict__ mask, int* __restrict__ L)
{
    const int b = blockIdx.x;
    const int t = threadIdx.x;
    const bool u8 = (mask[1] != 0);
    int cnt = 0;
    if (u8) {
        for (int n = t; n < N_; n += 256)
            cnt += (mask[(size_t)b * N_ + n] != 0) ? 1 : 0;
    } else {
        const int* mi = (const int*)mask;
        for (int n = t; n < N_; n += 256)
            cnt += (mi[(size_t)b * N_ + n] != 0) ? 1 : 0;
    }
    __shared__ int red[256];
    red[t] = cnt;
    __syncthreads();
    for (int s = 128; s > 0; s >>= 1) {
        if (t < s) red[t] += red[t + s];
        __syncthreads();
    }
    if (t == 0) L[b] = red[0];
}

// ---------------------------------------------------------------------------
// Shared NT-GEMM core: acc[8][8] += A_tile * B_tile^T over full K.
// A, Bw point at the tile's first row (row-major, leading dim = K).
// 128x128 block tile, 256 threads, 8x8 micro-tile per thread.
// ---------------------------------------------------------------------------
__device__ __forceinline__ void nt_core(const float* __restrict__ A,
                                        const float* __restrict__ Bw,
                                        int K, float (&acc)[8][8],
                                        float (*As)[BT], float (*Bs)[BT])
{
    const int tid = threadIdx.x;
    const int lr  = tid >> 2;          // 0..63  (tile row for staging)
    const int lk  = (tid & 3) << 2;    // 0,4,8,12
    const int tx  = tid & 15, ty = tid >> 4;

    const float* a0p = A + (size_t)lr * K + lk;
    const float* a1p = A + (size_t)(lr + 64) * K + lk;
    const float* b0p = Bw + (size_t)lr * K + lk;
    const float* b1p = Bw + (size_t)(lr + 64) * K + lk;

    for (int k0 = 0; k0 < K; k0 += KT) {
        const float4 a0 = *(const float4*)(a0p + k0);
        const float4 a1 = *(const float4*)(a1p + k0);
        const float4 b0 = *(const float4*)(b0p + k0);
        const float4 b1 = *(const float4*)(b1p + k0);
        __syncthreads();
        As[lk+0][lr] = a0.x; As[lk+1][lr] = a0.y; As[lk+2][lr] = a0.z; As[lk+3][lr] = a0.w;
        As[lk+0][lr+64] = a1.x; As[lk+1][lr+64] = a1.y; As[lk+2][lr+64] = a1.z; As[lk+3][lr+64] = a1.w;
        Bs[lk+0][lr] = b0.x; Bs[lk+1][lr] = b0.y; Bs[lk+2][lr] = b0.z; Bs[lk+3][lr] = b0.w;
        Bs[lk+0][lr+64] = b1.x; Bs[lk+1][lr+64] = b1.y; Bs[lk+2][lr+64] = b1.z; Bs[lk+3][lr+64] = b1.w;
        __syncthreads();
#pragma unroll
        for (int kk = 0; kk < KT; ++kk) {
            const float4 av0 = *(const float4*)&As[kk][ty * 4];
            const float4 av1 = *(const float4*)&As[kk][64 + ty * 4];
            const float4 bv0 = *(const float4*)&Bs[kk][tx * 4];
            const float4 bv1 = *(const float4*)&Bs[kk][64 + tx * 4];
            const float ar[8] = {av0.x, av0.y, av0.z, av0.w, av1.x, av1.y, av1.z, av1.w};
            const float br[8] = {bv0.x, bv0.y, bv0.z, bv0.w, bv1.x, bv1.y, bv1.z, bv1.w};
#pragma unroll
            for (int i = 0; i < 8; ++i)
#pragma unroll
                for (int j = 0; j < 8; ++j)
                    acc[i][j] = fmaf(ar[i], br[j], acc[i][j]);
        }
    }
}

// ---------------------------------------------------------------------------
// C[m,n] = alpha * sum_k A[m,k] * Bw[n,k]   (used for Q/K/V/out projections)
// ---------------------------------------------------------------------------
__global__ __launch_bounds__(256)
void gemm_nt(const float* __restrict__ A, const float* __restrict__ Bw,
             float* __restrict__ C, int Nc, int K, float alpha)
{
    __shared__ float As[KT][BT];
    __shared__ float Bs[KT][BT];
    const int m0 = blockIdx.y * BT, n0 = blockIdx.x * BT;
    float acc[8][8] = {};
    nt_core(A + (size_t)m0 * K, Bw + (size_t)n0 * K, K, acc, As, Bs);

    const int tx = threadIdx.x & 15, ty = threadIdx.x >> 4;
#pragma unroll
    for (int ih = 0; ih < 2; ++ih)
#pragma unroll
        for (int i = 0; i < 4; ++i) {
            const int m = m0 + ih * 64 + ty * 4 + i;
            const int r = ih * 4 + i;
            float* crow = C + (size_t)m * Nc + n0;
            *(float4*)(crow + tx * 4) =
                make_float4(alpha * acc[r][0], alpha * acc[r][1],
                            alpha * acc[r][2], alpha * acc[r][3]);
            *(float4*)(crow + 64 + tx * 4) =
                make_float4(alpha * acc[r][4], alpha * acc[r][5],
                            alpha * acc[r][6], alpha * acc[r][7]);
        }
}

// ---------------------------------------------------------------------------
// Masked logits: Att[b,i,j] = (i<L && j<L) ? Q[b,i,:]·K[b,j,:] : NEG
// (0.06 scale already folded into Q projection)
// ---------------------------------------------------------------------------
__global__ __launch_bounds__(256)
void gemm_logits(const float* __restrict__ Qm, const float* __restrict__ Km,
                 float* __restrict__ Att, const int* __restrict__ Lp)
{
    __shared__ float As[KT][BT];
    __shared__ float Bs[KT][BT];
    const int b  = blockIdx.z;
    const int m0 = blockIdx.y * BT, n0 = blockIdx.x * BT;
    const float* A  = Qm + (size_t)b * N_ * D_ + (size_t)m0 * D_;
    const float* Bw = Km + (size_t)b * N_ * D_ + (size_t)n0 * D_;
    float* C = Att + (size_t)b * N_ * N_;
    const int Lb = Lp[b];

    float acc[8][8] = {};
    nt_core(A, Bw, D_, acc, As, Bs);

    const int tx = threadIdx.x & 15, ty = threadIdx.x >> 4;
#pragma unroll
    for (int ih = 0; ih < 2; ++ih)
#pragma unroll
        for (int i = 0; i < 4; ++i) {
            const int m = m0 + ih * 64 + ty * 4 + i;
            const int r = ih * 4 + i;
            const bool mrow = (m < Lb);
            float* crow = C + (size_t)m * N_;
#pragma unroll
            for (int jh = 0; jh < 2; ++jh) {
                const int n = n0 + jh * 64 + tx * 4;
                float4 v;
                v.x = (mrow && (n + 0) < Lb) ? acc[r][jh * 4 + 0] : NEGV;
                v.y = (mrow && (n + 1) < Lb) ? acc[r][jh * 4 + 1] : NEGV;
                v.z = (mrow && (n + 2) < Lb) ? acc[r][jh * 4 + 2] : NEGV;
                v.w = (mrow && (n + 3) < Lb) ? acc[r][jh * 4 + 3] : NEGV;
                *(float4*)(crow + n) = v;
            }
        }
}

// ---------------------------------------------------------------------------
// In-place row softmax over last dim (N_=2048). One block per row.
// Fully-NEG rows come out exactly uniform 1/2048 (matches reference).
// ---------------------------------------------------------------------------
__global__ __launch_bounds__(256)
void softmax_rows(float* __restrict__ Att)
{
    const size_t row = blockIdx.x;
    float* p = Att + row * (size_t)N_;
    const int t = threadIdx.x;

    float4 v0 = *(float4*)(p + t * 4);
    float4 v1 = *(float4*)(p + 1024 + t * 4);

    float mx = fmaxf(fmaxf(fmaxf(v0.x, v0.y), fmaxf(v0.z, v0.w)),
                     fmaxf(fmaxf(v1.x, v1.y), fmaxf(v1.z, v1.w)));
#pragma unroll
    for (int o = 32; o > 0; o >>= 1) mx = fmaxf(mx, __shfl_xor(mx, o, 64));

    __shared__ float red[8];
    const int wv = t >> 6;
    if ((t & 63) == 0) red[wv] = mx;
    __syncthreads();
    mx = fmaxf(fmaxf(red[0], red[1]), fmaxf(red[2], red[3]));

    float e[8];
    e[0] = expf(v0.x - mx); e[1] = expf(v0.y - mx);
    e[2] = expf(v0.z - mx); e[3] = expf(v0.w - mx);
    e[4] = expf(v1.x - mx); e[5] = expf(v1.y - mx);
    e[6] = expf(v1.z - mx); e[7] = expf(v1.w - mx);
    float s = ((e[0] + e[1]) + (e[2] + e[3])) + ((e[4] + e[5]) + (e[6] + e[7]));
#pragma unroll
    for (int o = 32; o > 0; o >>= 1) s += __shfl_xor(s, o, 64);
    if ((t & 63) == 0) red[4 + wv] = s;
    __syncthreads();
    const float inv = 1.0f / (red[4] + red[5] + red[6] + red[7]);

    *(float4*)(p + t * 4)        = make_float4(e[0] * inv, e[1] * inv, e[2] * inv, e[3] * inv);
    *(float4*)(p + 1024 + t * 4) = make_float4(e[4] * inv, e[5] * inv, e[6] * inv, e[7] * inv);
}

// ---------------------------------------------------------------------------
// ctx[b,i,d] = sum_j Att[b,j,i] * V[b,j,d]   (A^T * V, both row-major)
// ---------------------------------------------------------------------------
__global__ __launch_bounds__(256)
void gemm_tn_ctx(const float* __restrict__ Att, const float* __restrict__ Vm,
                 float* __restrict__ C)
{
    __shared__ float As[KT][BT];
    __shared__ float Vs[KT][BT];
    const int b  = blockIdx.z;
    const int m0 = blockIdx.y * BT;   // over att column (output row i)
    const int n0 = blockIdx.x * BT;   // over D
    const float* A = Att + (size_t)b * N_ * N_;
    const float* V = Vm  + (size_t)b * N_ * D_;
    float* Co = C + (size_t)b * N_ * D_;

    const int tid = threadIdx.x;
    const int lk  = tid >> 5;          // 0..7
    const int lm  = (tid & 31) << 2;   // 0..124
    const int tx  = tid & 15, ty = tid >> 4;

    float acc[8][8] = {};
    for (int k0 = 0; k0 < N_; k0 += KT) {
        const float4 a0 = *(const float4*)(A + (size_t)(k0 + lk) * N_ + m0 + lm);
        const float4 a1 = *(const float4*)(A + (size_t)(k0 + lk + 8) * N_ + m0 + lm);
        const float4 w0 = *(const float4*)(V + (size_t)(k0 + lk) * D_ + n0 + lm);
        const float4 w1 = *(const float4*)(V + (size_t)(k0 + lk + 8) * D_ + n0 + lm);
        __syncthreads();
        *(float4*)&As[lk][lm]     = a0;
        *(float4*)&As[lk + 8][lm] = a1;
        *(float4*)&Vs[lk][lm]     = w0;
        *(float4*)&Vs[lk + 8][lm] = w1;
        __syncthreads();
#pragma unroll
        for (int kk = 0; kk < KT; ++kk) {
            const float4 av0 = *(const float4*)&As[kk][ty * 4];
            const float4 av1 = *(const float4*)&As[kk][64 + ty * 4];
            const float4 bv0 = *(const float4*)&Vs[kk][tx * 4];
            const float4 bv1 = *(const float4*)&Vs[kk][64 + tx * 4];
            const float ar[8] = {av0.x, av0.y, av0.z, av0.w, av1.x, av1.y, av1.z, av1.w};
            const float br[8] = {bv0.x, bv0.y, bv0.z, bv0.w, bv1.x, bv1.y, bv1.z, bv1.w};
#pragma unroll
            for (int i = 0; i < 8; ++i)
#pragma unroll
                for (int j = 0; j < 8; ++j)
                    acc[i][j] = fmaf(ar[i], br[j], acc[i][j]);
        }
    }

#pragma unroll
    for (int ih = 0; ih < 2; ++ih)
#pragma unroll
        for (int i = 0; i < 4; ++i) {
            const int m = m0 + ih * 64 + ty * 4 + i;
            const int r = ih * 4 + i;
            float* crow = Co + (size_t)m * D_ + n0;
            *(float4*)(crow + tx * 4) =
                make_float4(acc[r][0], acc[r][1], acc[r][2], acc[r][3]);
            *(float4*)(crow + 64 + tx * 4) =
                make_float4(acc[r][4], acc[r][5], acc[r][6], acc[r][7]);
        }
}

// ---------------------------------------------------------------------------
extern "C" void kernel_launch(void* const* d_in, const int* in_sizes, int n_in,
                              void* d_out, int out_size, void* d_ws, size_t ws_size,
                              hipStream_t stream)
{
    const float* x  = (const float*)d_in[0];
    const unsigned char* mask = (const unsigned char*)d_in[1];
    const float* Wq = (const float*)d_in[2];
    const float* Wk = (const float*)d_in[3];
    const float* Wv = (const float*)d_in[4];
    const float* Wo = (const float*)d_in[5];

    float* y   = (float*)d_out;                          // [B,N,D]
    float* att = (float*)d_out + (size_t)B_ * N_ * D_;   // [B,N,N]

    char* ws = (char*)d_ws;
    int*   L  = (int*)ws;
    float* Qb = (float*)(ws + 256);                      // 64 MB
    float* Kb = Qb + (size_t)B_ * N_ * D_;               // 64 MB
    float* Vb  = Kb;   // V projection reuses K buffer (K dead after logits)
    float* ctx = Qb;   // ctx reuses Q buffer (Q dead after logits)

    const dim3 blk(256);
    const int M = B_ * N_;

    k_lengths<<<dim3(B_), blk, 0, stream>>>(mask, L);
    gemm_nt<<<dim3(D_ / BT, M / BT), blk, 0, stream>>>(x, Wq, Qb, D_, D_, 0.06f);
    gemm_nt<<<dim3(D_ / BT, M / BT), blk, 0, stream>>>(x, Wk, Kb, D_, D_, 1.0f);
    gemm_logits<<<dim3(N_ / BT, N_ / BT, B_), blk, 0, stream>>>(Qb, Kb, att, L);
    softmax_rows<<<dim3(M), blk, 0, stream>>>(att);
    gemm_nt<<<dim3(D_ / BT, M / BT), blk, 0, stream>>>(x, Wv, Vb, D_, D_, 1.0f);
    gemm_tn_ctx<<<dim3(D_ / BT, N_ / BT, B_), blk, 0, stream>>>(att, Vb, ctx);
    gemm_nt<<<dim3(D_ / BT, M / BT), blk, 0, stream>>>(ctx, Wo, y, D_, D_, 1.0f);
}

// Round 2
// 771.976 us; speedup vs baseline: 4.3828x; 4.3828x over previous
//
#include <hip/hip_runtime.h>
#include <math.h>

typedef __attribute__((ext_vector_type(8))) short short8;
typedef __attribute__((ext_vector_type(4))) float f32x4;

namespace {
constexpr int B_ = 8;
constexpr int N_ = 2048;
constexpr int D_ = 1024;
constexpr float NEGV = -1.0e9f;
}

__device__ __forceinline__ unsigned short f2bf(float x) {
    union { float f; unsigned u; } v; v.f = x;
    unsigned u = v.u + 0x7fffu + ((v.u >> 16) & 1u);
    return (unsigned short)(u >> 16);
}

// ---------------------------------------------------------------------------
// Per-batch valid lengths from the prefix mask (uint8 or int32 layout).
// ---------------------------------------------------------------------------
__global__ __launch_bounds__(256)
void k_lengths(const unsigned char* __restrict__ mask, int* __restrict__ L)
{
    const int b = blockIdx.x;
    const int t = threadIdx.x;
    const bool u8 = (mask[1] != 0);
    int cnt = 0;
    if (u8) {
        for (int n = t; n < N_; n += 256)
            cnt += (mask[(size_t)b * N_ + n] != 0) ? 1 : 0;
    } else {
        const int* mi = (const int*)mask;
        for (int n = t; n < N_; n += 256)
            cnt += (mi[(size_t)b * N_ + n] != 0) ? 1 : 0;
    }
    __shared__ int red[256];
    red[t] = cnt;
    __syncthreads();
    for (int s = 128; s > 0; s >>= 1) {
        if (t < s) red[t] += red[t + s];
        __syncthreads();
    }
    if (t == 0) L[b] = red[0];
}

// ---------------------------------------------------------------------------
// f32 -> bf16 conversion (with optional scale), 1 float4 per thread.
// ---------------------------------------------------------------------------
__global__ __launch_bounds__(256)
void convert_bf16(const float* __restrict__ in, unsigned short* __restrict__ out,
                  int n4, float alpha)
{
    const int i = blockIdx.x * 256 + threadIdx.x;
    if (i >= n4) return;
    const float4 v = ((const float4*)in)[i];
    ushort4 o;
    o.x = f2bf(v.x * alpha); o.y = f2bf(v.y * alpha);
    o.z = f2bf(v.z * alpha); o.w = f2bf(v.w * alpha);
    ((ushort4*)out)[i] = o;
}

// ---------------------------------------------------------------------------
// bf16 MFMA NT-GEMM: C[m][n] = sum_k A[m][k] * B[n][k]
// 128x128 block tile, BK=32, 256 threads (4 waves, 2x2 of 64x64),
// 16x16x32 MFMA, global_load_lds width-16 staging.
// OUT_MODE: 0 = f32, 1 = bf16, 2 = f32 with prefix mask (logits)
// ---------------------------------------------------------------------------
template <int OUT_MODE>
__global__ __launch_bounds__(256)
void gemm_nt_mfma(const unsigned short* __restrict__ A, int lda, long strideA,
                  const unsigned short* __restrict__ Bm, int ldb, long strideB,
                  void* __restrict__ Cout, int ldc, long strideC,
                  int K, const int* __restrict__ Lp)
{
    __shared__ __attribute__((aligned(16))) short As[128 * 32];
    __shared__ __attribute__((aligned(16))) short Bs[128 * 32];

    const int tid  = threadIdx.x;
    const int lane = tid & 63;
    const int wave = tid >> 6;
    const int b    = blockIdx.z;
    const int m0   = blockIdx.y * 128;
    const int n0   = blockIdx.x * 128;

    const unsigned short* Ab = A  + (long)b * strideA;
    const unsigned short* Bb = Bm + (long)b * strideB;

    // staging: chunk c (0..511) covers 16B = 8 shorts; row = c>>2, seg = c&3
    const int rowL = tid >> 2;            // chunks 0..255  -> rows 0..63
    const int rowH = (tid + 256) >> 2;    // chunks 256..511-> rows 64..127
    const int seg  = (tid & 3) * 8;

    const unsigned short* gA0 = Ab + (long)(m0 + rowL) * lda + seg;
    const unsigned short* gA1 = Ab + (long)(m0 + rowH) * lda + seg;
    const unsigned short* gB0 = Bb + (long)(n0 + rowL) * ldb + seg;
    const unsigned short* gB1 = Bb + (long)(n0 + rowH) * ldb + seg;

    // wave-uniform LDS bases (bytes = chunk*16 -> shorts = chunk*8)
    short* lA0 = As + ((tid & ~63) + 0)   * 8;
    short* lA1 = As + ((tid & ~63) + 256) * 8;
    short* lB0 = Bs + ((tid & ~63) + 0)   * 8;
    short* lB1 = Bs + ((tid & ~63) + 256) * 8;

    const int q = lane >> 4, r = lane & 15;
    const int wm = (wave & 1) * 64, wn = (wave >> 1) * 64;

    const short* pa[4];
    const short* pb[4];
#pragma unroll
    for (int t = 0; t < 4; ++t) {
        pa[t] = As + (wm + t * 16 + r) * 32 + q * 8;
        pb[t] = Bs + (wn + t * 16 + r) * 32 + q * 8;
    }

    f32x4 acc[4][4] = {};

    for (int k0 = 0; k0 < K; k0 += 32) {
        __syncthreads();
        __builtin_amdgcn_global_load_lds(
            (const __attribute__((address_space(1))) void*)(gA0 + k0),
            (__attribute__((address_space(3))) void*)lA0, 16, 0, 0);
        __builtin_amdgcn_global_load_lds(
            (const __attribute__((address_space(1))) void*)(gB0 + k0),
            (__attribute__((address_space(3))) void*)lB0, 16, 0, 0);
        __builtin_amdgcn_global_load_lds(
            (const __attribute__((address_space(1))) void*)(gA1 + k0),
            (__attribute__((address_space(3))) void*)lA1, 16, 0, 0);
        __builtin_amdgcn_global_load_lds(
            (const __attribute__((address_space(1))) void*)(gB1 + k0),
            (__attribute__((address_space(3))) void*)lB1, 16, 0, 0);
        __syncthreads();

        short8 af[4], bf[4];
#pragma unroll
        for (int t = 0; t < 4; ++t) {
            af[t] = *(const short8*)pa[t];
            bf[t] = *(const short8*)pb[t];
        }
#pragma unroll
        for (int mt = 0; mt < 4; ++mt)
#pragma unroll
            for (int nt = 0; nt < 4; ++nt)
                acc[mt][nt] = __builtin_amdgcn_mfma_f32_16x16x32_bf16(
                    af[mt], bf[nt], acc[mt][nt], 0, 0, 0);
    }

    // epilogue: C/D layout col = lane&15, row = (lane>>4)*4 + reg
    if (OUT_MODE == 1) {
        unsigned short* C = (unsigned short*)Cout + (long)b * strideC;
#pragma unroll
        for (int mt = 0; mt < 4; ++mt)
#pragma unroll
            for (int nt = 0; nt < 4; ++nt)
#pragma unroll
                for (int rr = 0; rr < 4; ++rr) {
                    const int grow = m0 + wm + mt * 16 + q * 4 + rr;
                    const int gcol = n0 + wn + nt * 16 + r;
                    C[(long)grow * ldc + gcol] = f2bf(acc[mt][nt][rr]);
                }
    } else if (OUT_MODE == 0) {
        float* C = (float*)Cout + (long)b * strideC;
#pragma unroll
        for (int mt = 0; mt < 4; ++mt)
#pragma unroll
            for (int nt = 0; nt < 4; ++nt)
#pragma unroll
                for (int rr = 0; rr < 4; ++rr) {
                    const int grow = m0 + wm + mt * 16 + q * 4 + rr;
                    const int gcol = n0 + wn + nt * 16 + r;
                    C[(long)grow * ldc + gcol] = acc[mt][nt][rr];
                }
    } else {
        const int Lb = Lp[b];
        float* C = (float*)Cout + (long)b * strideC;
#pragma unroll
        for (int mt = 0; mt < 4; ++mt)
#pragma unroll
            for (int nt = 0; nt < 4; ++nt)
#pragma unroll
                for (int rr = 0; rr < 4; ++rr) {
                    const int grow = m0 + wm + mt * 16 + q * 4 + rr;
                    const int gcol = n0 + wn + nt * 16 + r;
                    const float val = (grow < Lb && gcol < Lb) ? acc[mt][nt][rr] : NEGV;
                    C[(long)grow * ldc + gcol] = val;
                }
    }
}

// ---------------------------------------------------------------------------
// In-place row softmax over last dim (N_=2048). One block per row.
// ---------------------------------------------------------------------------
__global__ __launch_bounds__(256)
void softmax_rows(float* __restrict__ Att)
{
    const size_t row = blockIdx.x;
    float* p = Att + row * (size_t)N_;
    const int t = threadIdx.x;

    float4 v0 = *(float4*)(p + t * 4);
    float4 v1 = *(float4*)(p + 1024 + t * 4);

    float mx = fmaxf(fmaxf(fmaxf(v0.x, v0.y), fmaxf(v0.z, v0.w)),
                     fmaxf(fmaxf(v1.x, v1.y), fmaxf(v1.z, v1.w)));
#pragma unroll
    for (int o = 32; o > 0; o >>= 1) mx = fmaxf(mx, __shfl_xor(mx, o, 64));

    __shared__ float red[8];
    const int wv = t >> 6;
    if ((t & 63) == 0) red[wv] = mx;
    __syncthreads();
    mx = fmaxf(fmaxf(red[0], red[1]), fmaxf(red[2], red[3]));

    float e[8];
    e[0] = expf(v0.x - mx); e[1] = expf(v0.y - mx);
    e[2] = expf(v0.z - mx); e[3] = expf(v0.w - mx);
    e[4] = expf(v1.x - mx); e[5] = expf(v1.y - mx);
    e[6] = expf(v1.z - mx); e[7] = expf(v1.w - mx);
    float s = ((e[0] + e[1]) + (e[2] + e[3])) + ((e[4] + e[5]) + (e[6] + e[7]));
#pragma unroll
    for (int o = 32; o > 0; o >>= 1) s += __shfl_xor(s, o, 64);
    if ((t & 63) == 0) red[4 + wv] = s;
    __syncthreads();
    const float inv = 1.0f / (red[4] + red[5] + red[6] + red[7]);

    *(float4*)(p + t * 4)        = make_float4(e[0] * inv, e[1] * inv, e[2] * inv, e[3] * inv);
    *(float4*)(p + 1024 + t * 4) = make_float4(e[4] * inv, e[5] * inv, e[6] * inv, e[7] * inv);
}

// ---------------------------------------------------------------------------
// att f32 [b][j][i] -> attT bf16 [b][i][j], 64x64 LDS tile transpose.
// ---------------------------------------------------------------------------
__global__ __launch_bounds__(256)
void transpose_att_bf16(const float* __restrict__ att, unsigned short* __restrict__ attT)
{
    __shared__ float tile[64][65];
    const int b  = blockIdx.z;
    const int j0 = blockIdx.y * 64;
    const int i0 = blockIdx.x * 64;
    const float* src = att + (long)b * N_ * N_;
    unsigned short* dst = attT + (long)b * N_ * N_;
    const int t = threadIdx.x;
#pragma unroll
    for (int l = 0; l < 4; ++l) {
        const int idx = t + l * 256;
        const int jj = idx >> 4;
        const int i4 = (idx & 15) * 4;
        const float4 v = *(const float4*)(src + (long)(j0 + jj) * N_ + i0 + i4);
        tile[i4 + 0][jj] = v.x;
        tile[i4 + 1][jj] = v.y;
        tile[i4 + 2][jj] = v.z;
        tile[i4 + 3][jj] = v.w;
    }
    __syncthreads();
#pragma unroll
    for (int l = 0; l < 4; ++l) {
        const int idx = t + l * 256;
        const int ii = idx >> 4;
        const int j4 = (idx & 15) * 4;
        ushort4 o;
        o.x = f2bf(tile[ii][j4 + 0]);
        o.y = f2bf(tile[ii][j4 + 1]);
        o.z = f2bf(tile[ii][j4 + 2]);
        o.w = f2bf(tile[ii][j4 + 3]);
        *(ushort4*)(dst + (long)(i0 + ii) * N_ + j0 + j4) = o;
    }
}

// ---------------------------------------------------------------------------
extern "C" void kernel_launch(void* const* d_in, const int* in_sizes, int n_in,
                              void* d_out, int out_size, void* d_ws, size_t ws_size,
                              hipStream_t stream)
{
    const float* x  = (const float*)d_in[0];
    const unsigned char* mask = (const unsigned char*)d_in[1];
    const float* Wq = (const float*)d_in[2];
    const float* Wk = (const float*)d_in[3];
    const float* Wv = (const float*)d_in[4];
    const float* Wo = (const float*)d_in[5];

    float* y   = (float*)d_out;                          // [B,N,D] f32
    float* att = (float*)d_out + (size_t)B_ * N_ * D_;   // [B,N,N] f32

    char* ws = (char*)d_ws;
    int* L = (int*)ws;
    unsigned short* Wqb = (unsigned short*)(ws + 256);
    unsigned short* Wkb = Wqb + 1048576;
    unsigned short* Wvb = Wkb + 1048576;
    unsigned short* Wob = Wvb + 1048576;
    unsigned short* xb  = Wob + 1048576;         // [16384,1024] bf16
    unsigned short* Qb  = xb + 16777216;         // [B*N, D]
    unsigned short* Kb  = Qb + 16777216;         // [B*N, D]
    unsigned short* VT  = Kb + 16777216;         // [D, B*N]
    unsigned short* attT = Qb;                   // [B, N, N] bf16 (reuses Qb+Kb)
    unsigned short* ctx  = xb;                   // [B*N, D] bf16 (reuses xb)

    const dim3 blk(256);
    const long ND = (long)N_ * D_;
    const long NN = (long)N_ * N_;

    k_lengths<<<dim3(B_), blk, 0, stream>>>(mask, L);

    convert_bf16<<<dim3(16384), blk, 0, stream>>>(x,  xb,  4194304, 1.0f);
    convert_bf16<<<dim3(1024),  blk, 0, stream>>>(Wq, Wqb, 262144, 0.06f);
    convert_bf16<<<dim3(1024),  blk, 0, stream>>>(Wk, Wkb, 262144, 1.0f);
    convert_bf16<<<dim3(1024),  blk, 0, stream>>>(Wv, Wvb, 262144, 1.0f);
    convert_bf16<<<dim3(1024),  blk, 0, stream>>>(Wo, Wob, 262144, 1.0f);

    // Q = x Wq^T * 0.06 ; K = x Wk^T   (bf16 out)
    gemm_nt_mfma<1><<<dim3(8, 128, 1), blk, 0, stream>>>(
        xb, D_, 0, Wqb, D_, 0, Qb, D_, 0, D_, nullptr);
    gemm_nt_mfma<1><<<dim3(8, 128, 1), blk, 0, stream>>>(
        xb, D_, 0, Wkb, D_, 0, Kb, D_, 0, D_, nullptr);

    // logits = Q K^T with prefix mask (f32 out into att region)
    gemm_nt_mfma<2><<<dim3(16, 16, B_), blk, 0, stream>>>(
        Qb, D_, ND, Kb, D_, ND, att, N_, NN, D_, L);

    softmax_rows<<<dim3(B_ * N_), blk, 0, stream>>>(att);

    // attT bf16 (reuses Qb/Kb space)
    transpose_att_bf16<<<dim3(32, 32, B_), blk, 0, stream>>>(att, attT);

    // VT = Wv x^T  -> [D, B*N] bf16
    gemm_nt_mfma<1><<<dim3(128, 8, 1), blk, 0, stream>>>(
        Wvb, D_, 0, xb, D_, 0, VT, B_ * N_, 0, D_, nullptr);

    // ctx[b][i][d] = sum_j attT[b][i][j] * VT[d][b*N + j]   (bf16 out)
    gemm_nt_mfma<1><<<dim3(8, 16, B_), blk, 0, stream>>>(
        attT, N_, NN, VT, B_ * N_, N_, ctx, D_, ND, N_, nullptr);

    // y = ctx Wo^T (f32 out)
    gemm_nt_mfma<0><<<dim3(8, 128, 1), blk, 0, stream>>>(
        ctx, D_, 0, Wob, D_, 0, y, D_, 0, D_, nullptr);
}

// Round 3
// 770.082 us; speedup vs baseline: 4.3936x; 1.0025x over previous
//
#include <hip/hip_runtime.h>
#include <math.h>

typedef __attribute__((ext_vector_type(8))) short short8;
typedef __attribute__((ext_vector_type(4))) float f32x4;

namespace {
constexpr int B_ = 8;
constexpr int N_ = 2048;
constexpr int D_ = 1024;
constexpr float NEGV = -1.0e9f;
}

__device__ __forceinline__ unsigned short f2bf(float x) {
    union { float f; unsigned u; } v; v.f = x;
    unsigned u = v.u + 0x7fffu + ((v.u >> 16) & 1u);
    return (unsigned short)(u >> 16);
}

// ---------------------------------------------------------------------------
// Per-batch valid lengths from the prefix mask (uint8 or int32 layout).
// ---------------------------------------------------------------------------
__global__ __launch_bounds__(256)
void k_lengths(const unsigned char* __restrict__ mask, int* __restrict__ L)
{
    const int b = blockIdx.x;
    const int t = threadIdx.x;
    const bool u8 = (mask[1] != 0);
    int cnt = 0;
    if (u8) {
        for (int n = t; n < N_; n += 256)
            cnt += (mask[(size_t)b * N_ + n] != 0) ? 1 : 0;
    } else {
        const int* mi = (const int*)mask;
        for (int n = t; n < N_; n += 256)
            cnt += (mi[(size_t)b * N_ + n] != 0) ? 1 : 0;
    }
    __shared__ int red[256];
    red[t] = cnt;
    __syncthreads();
    for (int s = 128; s > 0; s >>= 1) {
        if (t < s) red[t] += red[t + s];
        __syncthreads();
    }
    if (t == 0) L[b] = red[0];
}

// ---------------------------------------------------------------------------
// f32 -> bf16 conversion (with optional scale), 1 float4 per thread.
// ---------------------------------------------------------------------------
__global__ __launch_bounds__(256)
void convert_bf16(const float* __restrict__ in, unsigned short* __restrict__ out,
                  int n4, float alpha)
{
    const int i = blockIdx.x * 256 + threadIdx.x;
    if (i >= n4) return;
    const float4 v = ((const float4*)in)[i];
    ushort4 o;
    o.x = f2bf(v.x * alpha); o.y = f2bf(v.y * alpha);
    o.z = f2bf(v.z * alpha); o.w = f2bf(v.w * alpha);
    ((ushort4*)out)[i] = o;
}

// ---------------------------------------------------------------------------
// bf16 MFMA NT-GEMM: C[m][n] = sum_k A[m][k] * B[n][k]
// 128x128 block tile, BK=32, 256 threads (4 waves, 2x2 of 64x64),
// 16x16x32 MFMA, global_load_lds width-16 staging.
//
// LDS geometry: row = 32 shorts (64 B). 16-B segment s_log of row m is
// stored at physical segment s_log ^ ((m>>1)&3). Fragment ds_read_b128 for
// lane (q=lane>>4, r=lane&15) then hits bank base 16*(r&1) + 4*(q^((r>>1)&3)):
// each 8-lane batch covers all 8 four-bank groups -> conflict-free.
// (Unswizzled layout was ~8-way conflicted: 8.4M SQ_LDS_BANK_CONFLICT/dispatch.)
//
// OUT_MODE: 0 = f32, 1 = bf16, 2 = f32 with prefix mask (logits)
// ---------------------------------------------------------------------------
template <int OUT_MODE>
__global__ __launch_bounds__(256)
void gemm_nt_mfma(const unsigned short* __restrict__ A, int lda, long strideA,
                  const unsigned short* __restrict__ Bm, int ldb, long strideB,
                  void* __restrict__ Cout, int ldc, long strideC,
                  int K, const int* __restrict__ Lp)
{
    __shared__ __attribute__((aligned(16))) short As[128 * 32];
    __shared__ __attribute__((aligned(16))) short Bs[128 * 32];

    const int tid  = threadIdx.x;
    const int lane = tid & 63;
    const int wave = tid >> 6;
    const int b    = blockIdx.z;
    const int m0   = blockIdx.y * 128;
    const int n0   = blockIdx.x * 128;

    const unsigned short* Ab = A  + (long)b * strideA;
    const unsigned short* Bb = Bm + (long)b * strideB;

    // staging: chunk c covers 16B; physical (row = c>>2, phys seg = c&3).
    // swizzle: logical (global) segment = (c&3) ^ ((c>>3)&3); identical for
    // c and c+256, so one seg value serves both halves.
    const int rowL = tid >> 2;            // chunks 0..255  -> rows 0..63
    const int rowH = (tid + 256) >> 2;    // chunks 256..511-> rows 64..127
    const int seg  = (((tid & 3) ^ ((tid >> 3) & 3)) * 8);

    const unsigned short* gA0 = Ab + (long)(m0 + rowL) * lda + seg;
    const unsigned short* gA1 = Ab + (long)(m0 + rowH) * lda + seg;
    const unsigned short* gB0 = Bb + (long)(n0 + rowL) * ldb + seg;
    const unsigned short* gB1 = Bb + (long)(n0 + rowH) * ldb + seg;

    // wave-uniform LDS bases (bytes = chunk*16 -> shorts = chunk*8)
    short* lA0 = As + ((tid & ~63) + 0)   * 8;
    short* lA1 = As + ((tid & ~63) + 256) * 8;
    short* lB0 = Bs + ((tid & ~63) + 0)   * 8;
    short* lB1 = Bs + ((tid & ~63) + 256) * 8;

    const int q = lane >> 4, r = lane & 15;
    const int wm = (wave & 1) * 64, wn = (wave >> 1) * 64;
    const int sphys = (q ^ ((r >> 1) & 3)) * 8;   // swizzled fragment segment

    const short* pa[4];
    const short* pb[4];
#pragma unroll
    for (int t = 0; t < 4; ++t) {
        pa[t] = As + (wm + t * 16 + r) * 32 + sphys;
        pb[t] = Bs + (wn + t * 16 + r) * 32 + sphys;
    }

    f32x4 acc[4][4] = {};

    for (int k0 = 0; k0 < K; k0 += 32) {
        __syncthreads();
        __builtin_amdgcn_global_load_lds(
            (const __attribute__((address_space(1))) void*)(gA0 + k0),
            (__attribute__((address_space(3))) void*)lA0, 16, 0, 0);
        __builtin_amdgcn_global_load_lds(
            (const __attribute__((address_space(1))) void*)(gB0 + k0),
            (__attribute__((address_space(3))) void*)lB0, 16, 0, 0);
        __builtin_amdgcn_global_load_lds(
            (const __attribute__((address_space(1))) void*)(gA1 + k0),
            (__attribute__((address_space(3))) void*)lA1, 16, 0, 0);
        __builtin_amdgcn_global_load_lds(
            (const __attribute__((address_space(1))) void*)(gB1 + k0),
            (__attribute__((address_space(3))) void*)lB1, 16, 0, 0);
        __syncthreads();

        short8 af[4], bf[4];
#pragma unroll
        for (int t = 0; t < 4; ++t) {
            af[t] = *(const short8*)pa[t];
            bf[t] = *(const short8*)pb[t];
        }
#pragma unroll
        for (int mt = 0; mt < 4; ++mt)
#pragma unroll
            for (int nt = 0; nt < 4; ++nt)
                acc[mt][nt] = __builtin_amdgcn_mfma_f32_16x16x32_bf16(
                    af[mt], bf[nt], acc[mt][nt], 0, 0, 0);
    }

    // epilogue: C/D layout col = lane&15, row = (lane>>4)*4 + reg
    if (OUT_MODE == 1) {
        unsigned short* C = (unsigned short*)Cout + (long)b * strideC;
#pragma unroll
        for (int mt = 0; mt < 4; ++mt)
#pragma unroll
            for (int nt = 0; nt < 4; ++nt)
#pragma unroll
                for (int rr = 0; rr < 4; ++rr) {
                    const int grow = m0 + wm + mt * 16 + q * 4 + rr;
                    const int gcol = n0 + wn + nt * 16 + r;
                    C[(long)grow * ldc + gcol] = f2bf(acc[mt][nt][rr]);
                }
    } else if (OUT_MODE == 0) {
        float* C = (float*)Cout + (long)b * strideC;
#pragma unroll
        for (int mt = 0; mt < 4; ++mt)
#pragma unroll
            for (int nt = 0; nt < 4; ++nt)
#pragma unroll
                for (int rr = 0; rr < 4; ++rr) {
                    const int grow = m0 + wm + mt * 16 + q * 4 + rr;
                    const int gcol = n0 + wn + nt * 16 + r;
                    C[(long)grow * ldc + gcol] = acc[mt][nt][rr];
                }
    } else {
        const int Lb = Lp[b];
        float* C = (float*)Cout + (long)b * strideC;
#pragma unroll
        for (int mt = 0; mt < 4; ++mt)
#pragma unroll
            for (int nt = 0; nt < 4; ++nt)
#pragma unroll
                for (int rr = 0; rr < 4; ++rr) {
                    const int grow = m0 + wm + mt * 16 + q * 4 + rr;
                    const int gcol = n0 + wn + nt * 16 + r;
                    const float val = (grow < Lb && gcol < Lb) ? acc[mt][nt][rr] : NEGV;
                    C[(long)grow * ldc + gcol] = val;
                }
    }
}

// ---------------------------------------------------------------------------
// In-place row softmax over last dim (N_=2048). One block per row.
// ---------------------------------------------------------------------------
__global__ __launch_bounds__(256)
void softmax_rows(float* __restrict__ Att)
{
    const size_t row = blockIdx.x;
    float* p = Att + row * (size_t)N_;
    const int t = threadIdx.x;

    float4 v0 = *(float4*)(p + t * 4);
    float4 v1 = *(float4*)(p + 1024 + t * 4);

    float mx = fmaxf(fmaxf(fmaxf(v0.x, v0.y), fmaxf(v0.z, v0.w)),
                     fmaxf(fmaxf(v1.x, v1.y), fmaxf(v1.z, v1.w)));
#pragma unroll
    for (int o = 32; o > 0; o >>= 1) mx = fmaxf(mx, __shfl_xor(mx, o, 64));

    __shared__ float red[8];
    const int wv = t >> 6;
    if ((t & 63) == 0) red[wv] = mx;
    __syncthreads();
    mx = fmaxf(fmaxf(red[0], red[1]), fmaxf(red[2], red[3]));

    float e[8];
    e[0] = expf(v0.x - mx); e[1] = expf(v0.y - mx);
    e[2] = expf(v0.z - mx); e[3] = expf(v0.w - mx);
    e[4] = expf(v1.x - mx); e[5] = expf(v1.y - mx);
    e[6] = expf(v1.z - mx); e[7] = expf(v1.w - mx);
    float s = ((e[0] + e[1]) + (e[2] + e[3])) + ((e[4] + e[5]) + (e[6] + e[7]));
#pragma unroll
    for (int o = 32; o > 0; o >>= 1) s += __shfl_xor(s, o, 64);
    if ((t & 63) == 0) red[4 + wv] = s;
    __syncthreads();
    const float inv = 1.0f / (red[4] + red[5] + red[6] + red[7]);

    *(float4*)(p + t * 4)        = make_float4(e[0] * inv, e[1] * inv, e[2] * inv, e[3] * inv);
    *(float4*)(p + 1024 + t * 4) = make_float4(e[4] * inv, e[5] * inv, e[6] * inv, e[7] * inv);
}

// ---------------------------------------------------------------------------
// att f32 [b][j][i] -> attT bf16 [b][i][j], 64x64 LDS tile transpose.
// ---------------------------------------------------------------------------
__global__ __launch_bounds__(256)
void transpose_att_bf16(const float* __restrict__ att, unsigned short* __restrict__ attT)
{
    __shared__ float tile[64][65];
    const int b  = blockIdx.z;
    const int j0 = blockIdx.y * 64;
    const int i0 = blockIdx.x * 64;
    const float* src = att + (long)b * N_ * N_;
    unsigned short* dst = attT + (long)b * N_ * N_;
    const int t = threadIdx.x;
#pragma unroll
    for (int l = 0; l < 4; ++l) {
        const int idx = t + l * 256;
        const int jj = idx >> 4;
        const int i4 = (idx & 15) * 4;
        const float4 v = *(const float4*)(src + (long)(j0 + jj) * N_ + i0 + i4);
        tile[i4 + 0][jj] = v.x;
        tile[i4 + 1][jj] = v.y;
        tile[i4 + 2][jj] = v.z;
        tile[i4 + 3][jj] = v.w;
    }
    __syncthreads();
#pragma unroll
    for (int l = 0; l < 4; ++l) {
        const int idx = t + l * 256;
        const int ii = idx >> 4;
        const int j4 = (idx & 15) * 4;
        ushort4 o;
        o.x = f2bf(tile[ii][j4 + 0]);
        o.y = f2bf(tile[ii][j4 + 1]);
        o.z = f2bf(tile[ii][j4 + 2]);
        o.w = f2bf(tile[ii][j4 + 3]);
        *(ushort4*)(dst + (long)(i0 + ii) * N_ + j0 + j4) = o;
    }
}

// ---------------------------------------------------------------------------
extern "C" void kernel_launch(void* const* d_in, const int* in_sizes, int n_in,
                              void* d_out, int out_size, void* d_ws, size_t ws_size,
                              hipStream_t stream)
{
    const float* x  = (const float*)d_in[0];
    const unsigned char* mask = (const unsigned char*)d_in[1];
    const float* Wq = (const float*)d_in[2];
    const float* Wk = (const float*)d_in[3];
    const float* Wv = (const float*)d_in[4];
    const float* Wo = (const float*)d_in[5];

    float* y   = (float*)d_out;                          // [B,N,D] f32
    float* att = (float*)d_out + (size_t)B_ * N_ * D_;   // [B,N,N] f32

    char* ws = (char*)d_ws;
    int* L = (int*)ws;
    unsigned short* Wqb = (unsigned short*)(ws + 256);
    unsigned short* Wkb = Wqb + 1048576;
    unsigned short* Wvb = Wkb + 1048576;
    unsigned short* Wob = Wvb + 1048576;
    unsigned short* xb  = Wob + 1048576;         // [16384,1024] bf16
    unsigned short* Qb  = xb + 16777216;         // [B*N, D]
    unsigned short* Kb  = Qb + 16777216;         // [B*N, D]
    unsigned short* VT  = Kb + 16777216;         // [D, B*N]
    unsigned short* attT = Qb;                   // [B, N, N] bf16 (reuses Qb+Kb)
    unsigned short* ctx  = xb;                   // [B*N, D] bf16 (reuses xb)

    const dim3 blk(256);
    const long ND = (long)N_ * D_;
    const long NN = (long)N_ * N_;

    k_lengths<<<dim3(B_), blk, 0, stream>>>(mask, L);

    convert_bf16<<<dim3(16384), blk, 0, stream>>>(x,  xb,  4194304, 1.0f);
    convert_bf16<<<dim3(1024),  blk, 0, stream>>>(Wq, Wqb, 262144, 0.06f);
    convert_bf16<<<dim3(1024),  blk, 0, stream>>>(Wk, Wkb, 262144, 1.0f);
    convert_bf16<<<dim3(1024),  blk, 0, stream>>>(Wv, Wvb, 262144, 1.0f);
    convert_bf16<<<dim3(1024),  blk, 0, stream>>>(Wo, Wob, 262144, 1.0f);

    // Q = x Wq^T * 0.06 ; K = x Wk^T   (bf16 out)
    gemm_nt_mfma<1><<<dim3(8, 128, 1), blk, 0, stream>>>(
        xb, D_, 0, Wqb, D_, 0, Qb, D_, 0, D_, nullptr);
    gemm_nt_mfma<1><<<dim3(8, 128, 1), blk, 0, stream>>>(
        xb, D_, 0, Wkb, D_, 0, Kb, D_, 0, D_, nullptr);

    // logits = Q K^T with prefix mask (f32 out into att region)
    gemm_nt_mfma<2><<<dim3(16, 16, B_), blk, 0, stream>>>(
        Qb, D_, ND, Kb, D_, ND, att, N_, NN, D_, L);

    softmax_rows<<<dim3(B_ * N_), blk, 0, stream>>>(att);

    // attT bf16 (reuses Qb/Kb space)
    transpose_att_bf16<<<dim3(32, 32, B_), blk, 0, stream>>>(att, attT);

    // VT = Wv x^T  -> [D, B*N] bf16
    gemm_nt_mfma<1><<<dim3(128, 8, 1), blk, 0, stream>>>(
        Wvb, D_, 0, xb, D_, 0, VT, B_ * N_, 0, D_, nullptr);

    // ctx[b][i][d] = sum_j attT[b][i][j] * VT[d][b*N + j]   (bf16 out)
    gemm_nt_mfma<1><<<dim3(8, 16, B_), blk, 0, stream>>>(
        attT, N_, NN, VT, B_ * N_, N_, ctx, D_, ND, N_, nullptr);

    // y = ctx Wo^T (f32 out)
    gemm_nt_mfma<0><<<dim3(8, 128, 1), blk, 0, stream>>>(
        ctx, D_, 0, Wob, D_, 0, y, D_, 0, D_, nullptr);
}